// Round 9
// baseline (209.847 us; speedup 1.0000x reference)
//
#include <hip/hip_runtime.h>
#include <hip/hip_bf16.h>

typedef __attribute__((ext_vector_type(4))) float f32x4;
typedef __attribute__((ext_vector_type(8))) short bf16x8;
typedef __attribute__((ext_vector_type(8))) unsigned short u16x8;

// ---- workspace layout (bytes) ----
#define OFF_QS    0ull                     // [131072][128] bf16  q softmaxed * 1/sqrt(32)
#define OFF_EK    33554432ull              // [4 h][131072 n][32 d] bf16  exp(k), head-split
#define OFF_VV    67108864ull              // [4 h][131072 n][32 e] bf16  v, head-split
#define OFF_PCTX  100663296ull             // [16][128][32][32] f32 chunk partials
#define OFF_PSE   109051904ull             // [16][128][32] f32 chunk sum-exp
#define OFF_CTXG  109314048ull             // [32][4][32][32] bf16 normalized ctx
#define OFF_WQT   109576192ull             // [384][128] bf16 (W_qkv^T)
#define OFF_WOT   109674496ull             // [128][128] bf16 (W_out^T)
// total 109707264 bytes (~104.6 MiB)

static __device__ __forceinline__ unsigned short f2bf(float f) {
  unsigned int u = __builtin_bit_cast(unsigned int, f);
  return (unsigned short)((u + 0x7fffu + ((u >> 16) & 1u)) >> 16);  // RNE
}
static __device__ __forceinline__ float bf2f(unsigned short v) {
  return __builtin_bit_cast(float, (unsigned int)v << 16);
}

// ---------------- k_prep: weights -> bf16, transposed for B-fragments ----------------
__global__ __launch_bounds__(256) void k_prep(const float* __restrict__ wqkv,
                                              const float* __restrict__ wout,
                                              unsigned short* __restrict__ wqT,
                                              unsigned short* __restrict__ woT) {
  int idx = blockIdx.x * 256 + threadIdx.x;   // grid covers exactly 65536
  if (idx < 49152) {                          // wqT[f][k] = wqkv[k][f]
    int f = idx >> 7, k = idx & 127;
    wqT[idx] = f2bf(wqkv[k * 384 + f]);
  } else {                                    // woT[c][k] = wout[k][c]
    int j = idx - 49152;
    int c = j >> 7, k = j & 127;
    woT[j] = f2bf(wout[k * 128 + c]);
  }
}

// ---------------- k_qkv: one SECTION (q|k|v), 64-row tiles; 48KB LDS -> 3 blocks/CU ----
// Round-8 was LDS-capped at 2 blocks/CU (occ 36%, no pipe >39%). 64-row A tile (16KB)
// + 32KB W slice = 48KB -> 24 waves/CU. Flush reuses dead W region (needs 16KB).
__global__ __launch_bounds__(512, 6) void k_qkv(const float* __restrict__ x,
                                                const unsigned short* __restrict__ wqT,
                                                unsigned short* __restrict__ qs,
                                                unsigned short* __restrict__ ekh,
                                                unsigned short* __restrict__ vvh) {
  extern __shared__ char lds[];
  char* lds_w = lds;            // [128 f][128 k] bf16 swizzled, 32768 B; flush buf later
  char* lds_a = lds + 32768;    // [64 n][128 k] bf16 swizzled, 16384 B

  const int tid = threadIdx.x;
  const int tile = blockIdx.x;                 // 0..2047 (64-row tiles)
  const int sec = blockIdx.y;                  // 0=q 1=k 2=v
  const long rowbase = (long)tile * 64;

  {  // stage W slice rows [sec*128, +128): 2048 int4
    const int4* src = (const int4*)wqT + sec * 2048;
#pragma unroll
    for (int i = 0; i < 4; i++) {
      int u = tid + i * 512;                   // row f = u>>4
      ((int4*)lds_w)[u ^ ((u >> 4) & 7)] = src[u];
    }
  }
  {  // stage A: 64 rows, f32 -> bf16; 2048 f32x4 units, row = u>>5
    const f32x4* src = (const f32x4*)(x + rowbase * 128);
#pragma unroll
    for (int i = 0; i < 4; i++) {
      int u = tid + i * 512;
      f32x4 val = src[u];
      ushort4 bq;
      bq.x = f2bf(val.x); bq.y = f2bf(val.y); bq.z = f2bf(val.z); bq.w = f2bf(val.w);
      int ba = (u * 8) ^ (((u >> 5) & 7) << 4);
      *(ushort4*)(lds_a + ba) = bq;
    }
  }
  __syncthreads();

  const int lane = tid & 63, g = lane >> 4, c = lane & 15;
  const int wave = tid >> 6;
  const int wm = wave >> 1, wf = wave & 1;     // rows [16*wm,+16) x cols [64*wf,+64)

  f32x4 acc[4];
#pragma unroll
  for (int ft = 0; ft < 4; ft++) acc[ft] = (f32x4){0.f, 0.f, 0.f, 0.f};

#pragma unroll
  for (int kk = 0; kk < 4; kk++) {
    const int koff = (kk * 32 + g * 8) * 2;
    const int arow = wm * 16 + c;
    bf16x8 af = *(const bf16x8*)(lds_a + ((arow * 256 + koff) ^ ((arow & 7) << 4)));
#pragma unroll
    for (int ft = 0; ft < 4; ft++) {
      int frow = wf * 64 + ft * 16 + c;
      bf16x8 bfrag = *(const bf16x8*)(lds_w + ((frow * 256 + koff) ^ ((frow & 7) << 4)));
      acc[ft] = __builtin_amdgcn_mfma_f32_16x16x32_bf16(af, bfrag, acc[ft], 0, 0, 0);
    }
  }
  __syncthreads();                             // W reads done -> lds_w = flush buffer

  // epilogue into flush buffer [64 rows][128 cols] bf16, row-swizzled (16KB in lds_w)
  const float RS32 = 0.17677669529663687f;     // 1/sqrt(32)
#pragma unroll
  for (int j = 0; j < 2; j++) {                // ft pairs (2j,2j+1) = one 32-col head
    const int sc = wf * 64 + j * 32;
    f32x4 a0 = acc[2 * j], a1 = acc[2 * j + 1];
    const int row0 = wm * 16 + g * 4;
    if (sec == 0) {                            // q: softmax over the head's 32 dims
#pragma unroll
      for (int r = 0; r < 4; r++) {
        float e0 = __expf(a0[r]), e1 = __expf(a1[r]);
        float s = e0 + e1;
        s += __shfl_xor(s, 1); s += __shfl_xor(s, 2);
        s += __shfl_xor(s, 4); s += __shfl_xor(s, 8);
        float inv = RS32 / s;
        int row = row0 + r;
        *(unsigned short*)(lds + ((row * 256 + (sc + c) * 2)      ^ ((row & 7) << 4))) = f2bf(e0 * inv);
        *(unsigned short*)(lds + ((row * 256 + (sc + c + 16) * 2) ^ ((row & 7) << 4))) = f2bf(e1 * inv);
      }
    } else if (sec == 1) {                     // exp(k) (no max-sub: k ~ N(0,1))
#pragma unroll
      for (int r = 0; r < 4; r++) {
        int row = row0 + r;
        *(unsigned short*)(lds + ((row * 256 + (sc + c) * 2)      ^ ((row & 7) << 4))) = f2bf(__expf(a0[r]));
        *(unsigned short*)(lds + ((row * 256 + (sc + c + 16) * 2) ^ ((row & 7) << 4))) = f2bf(__expf(a1[r]));
      }
    } else {                                   // raw v
#pragma unroll
      for (int r = 0; r < 4; r++) {
        int row = row0 + r;
        *(unsigned short*)(lds + ((row * 256 + (sc + c) * 2)      ^ ((row & 7) << 4))) = f2bf(a0[r]);
        *(unsigned short*)(lds + ((row * 256 + (sc + c + 16) * 2) ^ ((row & 7) << 4))) = f2bf(a1[r]);
      }
    }
  }
  __syncthreads();

  // cooperative flush: 1024 int4 (16KB)
  if (sec == 0) {                              // qs: [n][128] layout
    const long off16 = (long)tile * 1024;      // 16 int4 per row
#pragma unroll
    for (int i = 0; i < 2; i++) {
      int u = tid + i * 512;
      int row = u >> 4;
      int4 v = *(const int4*)(lds + ((u * 16) ^ ((row & 7) << 4)));
      ((int4*)qs)[off16 + u] = v;
    }
  } else {                                     // ek/vv: head-split [h][n][32]
    unsigned short* dsth = (sec == 1) ? ekh : vvh;
#pragma unroll
    for (int i = 0; i < 2; i++) {
      int u = tid + i * 512;
      int row = u >> 4, col16 = u & 15;
      int h = col16 >> 2, q4 = col16 & 3;
      int4 v = *(const int4*)(lds + ((u * 16) ^ ((row & 7) << 4)));
      long di = ((long)h * 131072 + tile * 64 + row) * 4 + q4;   // int4 units
      ((int4*)dsth)[di] = v;
    }
  }
}

// ---------------- k_ctx: EK^T*V via MFMA; 16 partials per (b,h) ----------------
__global__ __launch_bounds__(256, 4) void k_ctx(const unsigned short* __restrict__ ekh,
                                                const unsigned short* __restrict__ vvh,
                                                float* __restrict__ pctx,
                                                float* __restrict__ pse) {
  extern __shared__ char lds[];                // ekT @0 (16KB), vT @16384 (16KB)

  const int tid = threadIdx.x;
  const int h = blockIdx.x & 3, quarter = blockIdx.x >> 2, b = blockIdx.y;
  const int wave = tid >> 6, lane = tid & 63, g = lane >> 4, c = lane & 15;
  const long nbase = (long)b * 4096 + quarter * 1024;

  f32x4 acc[2][2];
#pragma unroll
  for (int dt = 0; dt < 2; dt++) { acc[dt][0] = (f32x4){0.f,0.f,0.f,0.f}; acc[dt][1] = (f32x4){0.f,0.f,0.f,0.f}; }
  float se[2] = {0.f, 0.f};

  for (int sci = 0; sci < 4; sci++) {
    const long n0 = nbase + sci * 256;
    const uint4* esrc = (const uint4*)(ekh + ((long)h * 131072 + n0 + tid) * 32);
    const uint4* vsrc = (const uint4*)(vvh + ((long)h * 131072 + n0 + tid) * 32);
    uint4 ev[4], vq[4];
#pragma unroll
    for (int i = 0; i < 4; i++) { ev[i] = esrc[i]; vq[i] = vsrc[i]; }

    if (sci > 0) __syncthreads();              // prev MFMA reads done before overwrite

#pragma unroll
    for (int i = 0; i < 4; i++) {
      u16x8 es = __builtin_bit_cast(u16x8, ev[i]);
      u16x8 vs = __builtin_bit_cast(u16x8, vq[i]);
#pragma unroll
      for (int j = 0; j < 8; j++) {
        int d = i * 8 + j;
        int ba = (d * 512 + tid * 2) ^ ((d & 7) << 4);
        *(unsigned short*)(lds + ba)         = es[j];
        *(unsigned short*)(lds + 16384 + ba) = vs[j];
      }
    }
    __syncthreads();

#pragma unroll
    for (int ks = 0; ks < 2; ks++) {
      const int noff = (wave * 64 + ks * 32 + g * 8) * 2;
      bf16x8 afr[2], bfr[2];
#pragma unroll
      for (int dt = 0; dt < 2; dt++) {
        int row = dt * 16 + c;
        afr[dt] = *(const bf16x8*)(lds + ((row * 512 + noff) ^ ((row & 7) << 4)));
      }
#pragma unroll
      for (int et = 0; et < 2; et++) {
        int row = et * 16 + c;
        bfr[et] = *(const bf16x8*)(lds + 16384 + ((row * 512 + noff) ^ ((row & 7) << 4)));
      }
#pragma unroll
      for (int dt = 0; dt < 2; dt++)
#pragma unroll
        for (int j = 0; j < 8; j++)
          se[dt] += bf2f((unsigned short)afr[dt][j]);
#pragma unroll
      for (int dt = 0; dt < 2; dt++)
#pragma unroll
        for (int et = 0; et < 2; et++)
          acc[dt][et] = __builtin_amdgcn_mfma_f32_16x16x32_bf16(afr[dt], bfr[et], acc[dt][et], 0, 0, 0);
    }
  }

  const int p = quarter * 4 + wave;
  const long pb = ((long)p * 128 + b * 4 + h) * 1024;
#pragma unroll
  for (int dt = 0; dt < 2; dt++)
#pragma unroll
    for (int et = 0; et < 2; et++)
#pragma unroll
      for (int r = 0; r < 4; r++)
        pctx[pb + (dt * 16 + g * 4 + r) * 32 + et * 16 + c] = acc[dt][et][r];

#pragma unroll
  for (int dt = 0; dt < 2; dt++) {
    se[dt] += __shfl_xor(se[dt], 16);
    se[dt] += __shfl_xor(se[dt], 32);
  }
  if (lane < 16) {
#pragma unroll
    for (int dt = 0; dt < 2; dt++)
      pse[((long)p * 128 + b * 4 + h) * 32 + dt * 16 + c] = se[dt];
  }
}

// ---------------- k_ctxred: reduce 16 partials, normalize, emit ctx bf16 ----------------
__global__ __launch_bounds__(256) void k_ctxred(const float* __restrict__ pctx,
                                                const float* __restrict__ pse,
                                                unsigned short* __restrict__ ctxg) {
  int idx = blockIdx.x * 256 + threadIdx.x;   // 131072 = 32*4*32*32
  int de = idx & 1023, d = de >> 5, bh = idx >> 10;
  float s = 0.f, sume = 0.f;
#pragma unroll
  for (int ch = 0; ch < 16; ch++) {
    s    += pctx[(ch * 128 + bh) * 1024 + de];
    sume += pse[(ch * 128 + bh) * 32 + d];
  }
  ctxg[idx] = f2bf(s / (sume * 4096.0f));     // softmax-normalize + v's 1/N
}

// ---------------- k_out: attn = q_s*ctx ; y = attn@Wout + b ; LayerNorm ----------------
// Wout B-fragments now read from global (L2-resident 32KB) -> one less stage, LDS 41KB.
__global__ __launch_bounds__(512, 2) void k_out(const unsigned short* __restrict__ qs,
                                                const unsigned short* __restrict__ ctxg,
                                                const unsigned short* __restrict__ woT,
                                                const float* __restrict__ bout,
                                                const float* __restrict__ lnsc,
                                                float* __restrict__ out) {
  extern __shared__ char lds[];
  char* lds_at = lds;                                       // 32768 B, swizzled [row][col]; f32 flush later
  unsigned short* lds_cx = (unsigned short*)(lds + 32768);  // [4][32 e][32 d] bf16, 8192 B
  float* lds_bias  = (float*)(lds + 40960);
  float* lds_scale = (float*)(lds + 41472);

  const int tid = threadIdx.x;
  const long rowbase = (long)blockIdx.x * 128;
  const int b = blockIdx.x >> 5;

  {  // stage ctx [h][d][e] -> LDS transposed [h][e][d]
    const unsigned int* src = (const unsigned int*)(ctxg + (long)b * 4096);
#pragma unroll
    for (int i = 0; i < 4; i++) {
      int u = tid + i * 512;           // one uint = elems (j, j+1), j = 2u
      unsigned int w = src[u];
      int j = u * 2;
      int e = j & 31, d = (j >> 5) & 31, h = j >> 10;
      lds_cx[(h * 32 + e) * 32 + d]     = (unsigned short)(w & 0xffffu);
      lds_cx[(h * 32 + e + 1) * 32 + d] = (unsigned short)(w >> 16);
    }
  }
  if (tid < 128) { lds_bias[tid] = bout[tid]; lds_scale[tid] = lnsc[tid]; }
  __syncthreads();

  const int lane = tid & 63, g = lane >> 4, c = lane & 15;
  const int wave = tid >> 6;

  // GEMM1: attn[16 rows][128] ; A = q_s from global, B = ctx from LDS
  f32x4 acc1[4][2];
#pragma unroll
  for (int h = 0; h < 4; h++) { acc1[h][0] = (f32x4){0.f,0.f,0.f,0.f}; acc1[h][1] = (f32x4){0.f,0.f,0.f,0.f}; }
  const unsigned short* qrow = qs + (rowbase + wave * 16 + c) * 128;
#pragma unroll
  for (int h = 0; h < 4; h++) {
    bf16x8 a = *(const bf16x8*)(qrow + h * 32 + g * 8);
#pragma unroll
    for (int et = 0; et < 2; et++) {
      bf16x8 bq = *(const bf16x8*)(lds_cx + (h * 32 + et * 16 + c) * 32 + g * 8);
      acc1[h][et] = __builtin_amdgcn_mfma_f32_16x16x32_bf16(a, bq, acc1[h][et], 0, 0, 0);
    }
  }
  {  // attn -> LDS (bf16, swizzled) for the A-fragment round trip
    int rowl = wave * 16 + g * 4;
#pragma unroll
    for (int h = 0; h < 4; h++)
#pragma unroll
      for (int et = 0; et < 2; et++) {
        int col = (2 * h + et) * 16 + c;
#pragma unroll
        for (int r = 0; r < 4; r++) {
          int row = rowl + r;
          int ba = (row * 256 + col * 2) ^ ((row & 7) << 4);
          *(unsigned short*)(lds_at + ba) = f2bf(acc1[h][et][r]);
        }
      }
  }
  __syncthreads();

  // GEMM2: y = attn @ Wout ; B-fragments straight from global woT (L2-resident)
  f32x4 acc2[8];
#pragma unroll
  for (int ct = 0; ct < 8; ct++) acc2[ct] = (f32x4){0.f,0.f,0.f,0.f};
#pragma unroll
  for (int kk = 0; kk < 4; kk++) {
    int koff = (kk * 32 + g * 8) * 2;
    int arow = wave * 16 + c;
    bf16x8 a = *(const bf16x8*)(lds_at + ((arow * 256 + koff) ^ ((arow & 7) << 4)));
#pragma unroll
    for (int ct = 0; ct < 8; ct++) {
      int wrow = ct * 16 + c;
      bf16x8 bw = *(const bf16x8*)(woT + wrow * 128 + kk * 32 + g * 8);
      acc2[ct] = __builtin_amdgcn_mfma_f32_16x16x32_bf16(a, bw, acc2[ct], 0, 0, 0);
    }
  }

  // bias + LayerNorm (per-row over 128 channels, shuffle reduction) -> keep in regs
  float biasv[8], scalev[8];
#pragma unroll
  for (int ct = 0; ct < 8; ct++) { biasv[ct] = lds_bias[ct * 16 + c]; scalev[ct] = lds_scale[ct * 16 + c]; }
#pragma unroll
  for (int ct = 0; ct < 8; ct++)
#pragma unroll
    for (int r = 0; r < 4; r++)
      acc2[ct][r] += biasv[ct];

#pragma unroll
  for (int r = 0; r < 4; r++) {
    float s = 0.f, ss = 0.f;
#pragma unroll
    for (int ct = 0; ct < 8; ct++) { float v = acc2[ct][r]; s += v; ss += v * v; }
    s  += __shfl_xor(s, 1);  s  += __shfl_xor(s, 2);  s  += __shfl_xor(s, 4);  s  += __shfl_xor(s, 8);
    ss += __shfl_xor(ss, 1); ss += __shfl_xor(ss, 2); ss += __shfl_xor(ss, 4); ss += __shfl_xor(ss, 8);
    float mu = s * 0.0078125f;
    float var = ss * 0.0078125f - mu * mu;
    float rstd = rsqrtf(var + 1e-5f);
#pragma unroll
    for (int ct = 0; ct < 8; ct++)
      acc2[ct][r] = (acc2[ct][r] - mu) * rstd * scalev[ct];
  }

  // coalesced store via lds_at (f32), two 64-row half-passes of 32KB each
#pragma unroll
  for (int half = 0; half < 2; half++) {
    __syncthreads();                     // lds_at free (after GEMM2 / previous flush)
    if ((wave >> 2) == half) {
      int rl0 = (wave & 3) * 16 + g * 4; // local row within half (0..63)
#pragma unroll
      for (int ct = 0; ct < 8; ct++)
#pragma unroll
        for (int r = 0; r < 4; r++) {
          int rl = rl0 + r;
          *(float*)(lds_at + ((rl * 512 + (ct * 16 + c) * 4) ^ ((rl & 7) << 4))) = acc2[ct][r];
        }
    }
    __syncthreads();
    {
      const long base = (rowbase + half * 64) * 32;   // int4 units (32 per 128-f32 row)
#pragma unroll
      for (int i = 0; i < 4; i++) {
        int u = tid + i * 512;
        int row = u >> 5;
        int4 v = *(const int4*)(lds_at + ((u * 16) ^ ((row & 7) << 4)));
        ((int4*)out)[base + u] = v;
      }
    }
  }
}

// ---------------- host ----------------
extern "C" void kernel_launch(void* const* d_in, const int* in_sizes, int n_in,
                              void* d_out, int out_size, void* d_ws, size_t ws_size,
                              hipStream_t stream) {
  (void)in_sizes; (void)n_in; (void)out_size; (void)ws_size;
  const float* x     = (const float*)d_in[0];
  const float* wqkv  = (const float*)d_in[1];
  const float* wout  = (const float*)d_in[2];
  const float* bo    = (const float*)d_in[3];
  const float* lnsc  = (const float*)d_in[4];
  float* out = (float*)d_out;

  char* ws = (char*)d_ws;
  unsigned short* qs   = (unsigned short*)(ws + OFF_QS);
  unsigned short* ekh  = (unsigned short*)(ws + OFF_EK);
  unsigned short* vvh  = (unsigned short*)(ws + OFF_VV);
  float*          pctx = (float*)(ws + OFF_PCTX);
  float*          pse  = (float*)(ws + OFF_PSE);
  unsigned short* ctxg = (unsigned short*)(ws + OFF_CTXG);
  unsigned short* wqT  = (unsigned short*)(ws + OFF_WQT);
  unsigned short* woT  = (unsigned short*)(ws + OFF_WOT);

  k_prep<<<dim3(256), dim3(256), 0, stream>>>(wqkv, wout, wqT, woT);
  k_qkv<<<dim3(2048, 3), dim3(512), 49152, stream>>>(x, wqT, qs, ekh, vvh);
  k_ctx<<<dim3(16, 32), dim3(256), 32768, stream>>>(ekh, vvh, pctx, pse);
  k_ctxred<<<dim3(512), dim3(256), 0, stream>>>(pctx, pse, ctxg);
  k_out<<<dim3(1024), dim3(512), 41984, stream>>>(qs, ctxg, woT, bo, lnsc, out);
}